// Round 7
// baseline (1081.812 us; speedup 1.0000x reference)
//
#include <hip/hip_runtime.h>

#define NGRIDF 4194304.0f      // 2^22
#define NSEG 5                 // 3.36 MB windows -> resident in 4 MB per-XCD L2
#define PTS 32                 // points per thread
#define BIAS 64.0f             // done-marker: store -(BIAS+rr) < 0
#define SEGW 838860.8f         // NGRIDF/NSEG: s-domain segment width

// Unaligned-capable 16B vector load (align-4 dwordx4 is legal on gfx9+)
typedef float f32x4u __attribute__((ext_vector_type(4), aligned(4)));

// Consume one gathered quad: recompute weights from s (cheap unconditional
// VALU; garbage for inactive lanes), commit via a single cndmask.
// fp path identical to R4/R5 (validated absmax 0.0625): sp2 = s+2 carries the
// reference's rounding; all subtractions provably exact.
__device__ __forceinline__ float consume(float s, bool act, f32x4u cv) {
    float sp2 = s + 2.0f;
    float bf  = floorf(s);
    float fr  = (sp2 - bf) - 2.0f;      // exact; in [0,1) for active lanes
    float om  = 1.0f - fr;              // exact
    float fr2 = fr * fr, fr3 = fr2 * fr;
    float om2 = om * om,  om3 = om2 * om;
    float w1 = fmaf(3.0f, fr3, fmaf(-6.0f, fr2, 4.0f));
    float w2 = fmaf(3.0f, om3, fmaf(-6.0f, om2, 4.0f));
    float rr = om3 * cv.x;
    rr = fmaf(w1,  cv.y, rr);
    rr = fmaf(w2,  cv.z, rr);
    rr = fmaf(fr3, cv.w, rr);
    return act ? (-BIAS - rr) : s;      // done-marker always < 0
}

// One segment-pass over a float4 group: phase 1 issues 4 exec-masked gathers
// (independent; loads stay in flight across exec toggles -- no waitcnt until
// use), phase 2 consumes with counted waitcnts. Only active lanes present
// addresses to the TA (the R6 lesson).
__device__ __forceinline__ void group_pass(float4& v, float lo,
                                           const float* __restrict__ c,
                                           f32x4u& c0, f32x4u& c1,
                                           f32x4u& c2, f32x4u& c3) {
    bool a0 = v.x >= lo, a1 = v.y >= lo, a2 = v.z >= lo, a3 = v.w >= lo;
    if (a0) c0 = *reinterpret_cast<const f32x4u*>(c + (int)v.x);
    if (a1) c1 = *reinterpret_cast<const f32x4u*>(c + (int)v.y);
    if (a2) c2 = *reinterpret_cast<const f32x4u*>(c + (int)v.z);
    if (a3) c3 = *reinterpret_cast<const f32x4u*>(c + (int)v.w);
    v.x = consume(v.x, a0, c0);
    v.y = consume(v.y, a1, c1);
    v.z = consume(v.z, a2, c2);
    v.w = consume(v.w, a3, c3);
}

// Single-cohort persistent sweep at full occupancy:
// 2048 blocks * 256 thr = 524288 threads = 8 blocks/CU * 4 waves = 32 waves/CU.
// State held in s-domain (p = x * 2^22, exact scale); descending segment sweep
// keeps the chip's gathers inside a ~3.4 MB L2-resident window per pass.
__global__ __launch_bounds__(256, 8) void spline_pipelined_kernel(
    const float* __restrict__ x, const float* __restrict__ c,
    float* __restrict__ out)
{
    const int t = threadIdx.x;
    const int blockBase = blockIdx.x * (8 * 256);   // in float4 units
    const float4* __restrict__ x4 = reinterpret_cast<const float4*>(x);
    float4* __restrict__ o4 = reinterpret_cast<float4*>(out);

    // Gather destination registers, hoisted: init once, masked loads update
    // only active lanes (stale contents for inactive lanes are discarded).
    f32x4u c0 = {0.f,0.f,0.f,0.f}, c1 = {0.f,0.f,0.f,0.f};
    f32x4u c2 = {0.f,0.f,0.f,0.f}, c3 = {0.f,0.f,0.f,0.f};

#define LD(i) float4 v##i = x4[blockBase + (i) * 256 + t]; \
              v##i.x *= NGRIDF; v##i.y *= NGRIDF; v##i.z *= NGRIDF; v##i.w *= NGRIDF;
    LD(0) LD(1) LD(2) LD(3) LD(4) LD(5) LD(6) LD(7)
#undef LD

    #pragma unroll 1
    for (int seg = NSEG - 1; seg >= 0; --seg) {     // descending: 1 cmp/test
        const float lo = (float)seg * SEGW;         // last pass lo == 0.0f
        group_pass(v0, lo, c, c0, c1, c2, c3);
        group_pass(v1, lo, c, c0, c1, c2, c3);
        group_pass(v2, lo, c, c0, c1, c2, c3);
        group_pass(v3, lo, c, c0, c1, c2, c3);
        group_pass(v4, lo, c, c0, c1, c2, c3);
        group_pass(v5, lo, c, c0, c1, c2, c3);
        group_pass(v6, lo, c, c0, c1, c2, c3);
        group_pass(v7, lo, c, c0, c1, c2, c3);
    }

    // Decode: stored = -(BIAS+rr); out = -stored - BIAS = rr.
#define ST(i) o4[blockBase + (i) * 256 + t] = \
        make_float4(-v##i.x - BIAS, -v##i.y - BIAS, -v##i.z - BIAS, -v##i.w - BIAS);
    ST(0) ST(1) ST(2) ST(3) ST(4) ST(5) ST(6) ST(7)
#undef ST
}

extern "C" void kernel_launch(void* const* d_in, const int* in_sizes, int n_in,
                              void* d_out, int out_size, void* d_ws, size_t ws_size,
                              hipStream_t stream) {
    const float* x = (const float*)d_in[0];
    const float* c = (const float*)d_in[1];
    float* out = (float*)d_out;
    int n = in_sizes[0];                 // 16777216
    int grid = n / (256 * PTS);          // 2048 blocks -> exactly resident

    spline_pipelined_kernel<<<grid, 256, 0, stream>>>(x, c, out);
}

// Round 8
// 203.666 us; speedup vs baseline: 5.3117x; 5.3117x over previous
//
#include <hip/hip_runtime.h>

#define NGRIDF 4194304.0f      // 2^22
#define NSEG 5                 // 3.36 MB windows -> resident in 4 MB per-XCD L2
#define PTS 32                 // points per thread
#define BIAS 64.0f             // done-marker: store -(BIAS+rr) < 0

// Unaligned-capable 16B vector load (align-4 dwordx4 is legal on gfx9+)
typedef float f32x4u __attribute__((ext_vector_type(4), aligned(4)));

// Weight+dot from an already-gathered quad. fp path identical to R4/R5
// (validated absmax 0.0625): s = x*2^22 exact; sp2 = s+2 carries the
// reference's rounding; all subtractions provably exact.
__device__ __forceinline__ float finish(float p, f32x4u cv) {
    float s   = p * NGRIDF;
    int   b   = (int)s;
    float sp2 = s + 2.0f;
    float g   = sp2 - (float)(b + 1);      // in [1,2)
    float fr  = g - 1.0f;                  // exact (Sterbenz)
    float om  = 1.0f - fr;
    float fr2 = fr * fr, fr3 = fr2 * fr;
    float om2 = om * om,  om3 = om2 * om;
    float w1 = fmaf(3.0f, fr3, fmaf(-6.0f, fr2, 4.0f));
    float w2 = fmaf(3.0f, om3, fmaf(-6.0f, om2, 4.0f));
    float rr = om3 * cv.x;
    rr = fmaf(w1,  cv.y, rr);
    rr = fmaf(w2,  cv.z, rr);
    rr = fmaf(fr3, cv.w, rr);
    return -BIAS - rr;                     // done-marker, always < 0
}

// One segment-pass over a float4 group. Issue phase: 4 exec-masked gathers
// back-to-back (only active lanes present addresses -- the R6 lesson; loads
// stay in flight across exec toggles). Consume phase: 4 masked finishes with
// counted waitcnts. cv* are SHORT-LIVED locals conditionally read under the
// same condition that wrote them -- they stay in VGPRs (the R7 lesson: no
// kernel-lifetime conditionally-merged vector state, no references).
__device__ __forceinline__ void group_pass(float4& v, float lo,
                                           const float* __restrict__ c) {
    bool a0 = v.x >= lo, a1 = v.y >= lo, a2 = v.z >= lo, a3 = v.w >= lo;
    f32x4u cv0, cv1, cv2, cv3;
    if (a0) cv0 = *reinterpret_cast<const f32x4u*>(c + (int)(v.x * NGRIDF));
    if (a1) cv1 = *reinterpret_cast<const f32x4u*>(c + (int)(v.y * NGRIDF));
    if (a2) cv2 = *reinterpret_cast<const f32x4u*>(c + (int)(v.z * NGRIDF));
    if (a3) cv3 = *reinterpret_cast<const f32x4u*>(c + (int)(v.w * NGRIDF));
    if (a0) v.x = finish(v.x, cv0);
    if (a1) v.y = finish(v.y, cv1);
    if (a2) v.z = finish(v.z, cv2);
    if (a3) v.w = finish(v.w, cv3);
}

// Single-cohort persistent sweep at full occupancy:
// 2048 blocks * 256 thr = 524288 threads = 8 blocks/CU * 4 waves = 32 waves/CU.
// All waves sweep the 5 coefficient segments together (descending lo), so the
// chip's gathers stay inside a ~3.4 MB L2-resident window per pass.
__global__ __launch_bounds__(256, 8) void spline_inflight_kernel(
    const float* __restrict__ x, const float* __restrict__ c,
    float* __restrict__ out)
{
    const int t = threadIdx.x;
    const int blockBase = blockIdx.x * (8 * 256);   // in float4 units
    const float4* __restrict__ x4 = reinterpret_cast<const float4*>(x);
    float4* __restrict__ o4 = reinterpret_cast<float4*>(out);

#define LD(i) float4 v##i = x4[blockBase + (i) * 256 + t];
    LD(0) LD(1) LD(2) LD(3) LD(4) LD(5) LD(6) LD(7)
#undef LD

    #pragma unroll 1
    for (int seg = NSEG - 1; seg >= 0; --seg) {     // descending: 1 cmp/test
        const float lo = (float)seg * 0.2f;         // last pass lo == 0.0f
        group_pass(v0, lo, c);
        group_pass(v1, lo, c);
        group_pass(v2, lo, c);
        group_pass(v3, lo, c);
        group_pass(v4, lo, c);
        group_pass(v5, lo, c);
        group_pass(v6, lo, c);
        group_pass(v7, lo, c);
    }

    // Decode: stored = -(BIAS+rr); out = -stored - BIAS = rr.
#define ST(i) o4[blockBase + (i) * 256 + t] = \
        make_float4(-v##i.x - BIAS, -v##i.y - BIAS, -v##i.z - BIAS, -v##i.w - BIAS);
    ST(0) ST(1) ST(2) ST(3) ST(4) ST(5) ST(6) ST(7)
#undef ST
}

extern "C" void kernel_launch(void* const* d_in, const int* in_sizes, int n_in,
                              void* d_out, int out_size, void* d_ws, size_t ws_size,
                              hipStream_t stream) {
    const float* x = (const float*)d_in[0];
    const float* c = (const float*)d_in[1];
    float* out = (float*)d_out;
    int n = in_sizes[0];                 // 16777216
    int grid = n / (256 * PTS);          // 2048 blocks -> exactly resident

    spline_inflight_kernel<<<grid, 256, 0, stream>>>(x, c, out);
}

// Round 9
// 173.758 us; speedup vs baseline: 6.2260x; 1.1721x over previous
//
#include <hip/hip_runtime.h>

#define NGRIDF 4194304.0f      // 2^22
#define NSEG 5                 // 3.36 MB windows -> resident in 4 MB per-XCD L2
#define PTS 32                 // points per thread
#define BIAS 64.0f             // done-marker: store -(BIAS+rr) < 0

// Unaligned-capable 16B vector load (align-4 dwordx4 is legal on gfx9+)
typedef float f32x4u __attribute__((ext_vector_type(4), aligned(4)));

// Weight+dot from an already-gathered quad. fp path identical to R4/R5
// (validated absmax 0.0625): s = x*2^22 exact; sp2 = s+2 carries the
// reference's rounding; all subtractions provably exact.
__device__ __forceinline__ float finish(float p, f32x4u cv) {
    float s   = p * NGRIDF;
    int   b   = (int)s;
    float sp2 = s + 2.0f;
    float g   = sp2 - (float)(b + 1);      // in [1,2)
    float fr  = g - 1.0f;                  // exact (Sterbenz)
    float om  = 1.0f - fr;
    float fr2 = fr * fr, fr3 = fr2 * fr;
    float om2 = om * om,  om3 = om2 * om;
    float w1 = fmaf(3.0f, fr3, fmaf(-6.0f, fr2, 4.0f));
    float w2 = fmaf(3.0f, om3, fmaf(-6.0f, om2, 4.0f));
    float rr = om3 * cv.x;
    rr = fmaf(w1,  cv.y, rr);
    rr = fmaf(w2,  cv.z, rr);
    rr = fmaf(fr3, cv.w, rr);
    return -BIAS - rr;                     // done-marker, always < 0
}

// Depth-2 pipelined pair-pass: issue BOTH exec-masked gathers back-to-back
// (only active lanes present addresses -- R6 lesson; loads stay in flight
// across exec toggles), then consume both. First consume's ~20 VALU ops
// hide the second load's L2 latency (counted vmcnt(1)/vmcnt(0)).
// cv0/cv1 are short-lived locals read under the same condition that wrote
// them -- they stay in VGPRs (R7/R8 lesson: depth must fit the 64-reg cap;
// depth-2 budget = 32 state + 8 cv + ~12 temps ~= 52).
__device__ __forceinline__ void pair_pass(float& p0, float& p1, float lo,
                                          const float* __restrict__ c) {
    bool a0 = p0 >= lo, a1 = p1 >= lo;
    f32x4u cv0, cv1;
    if (a0) cv0 = *reinterpret_cast<const f32x4u*>(c + (int)(p0 * NGRIDF));
    if (a1) cv1 = *reinterpret_cast<const f32x4u*>(c + (int)(p1 * NGRIDF));
    if (a0) p0 = finish(p0, cv0);
    if (a1) p1 = finish(p1, cv1);
}

// Single-cohort persistent sweep at full occupancy:
// 2048 blocks * 256 thr = 524288 threads = 8 blocks/CU * 4 waves = 32 waves/CU.
// All waves sweep the 5 coefficient segments together (descending lo), so the
// chip's gathers stay inside a ~3.4 MB L2-resident window per pass.
__global__ __launch_bounds__(256, 8) void spline_depth2_kernel(
    const float* __restrict__ x, const float* __restrict__ c,
    float* __restrict__ out)
{
    const int t = threadIdx.x;
    const int blockBase = blockIdx.x * (8 * 256);   // in float4 units
    const float4* __restrict__ x4 = reinterpret_cast<const float4*>(x);
    float4* __restrict__ o4 = reinterpret_cast<float4*>(out);

#define LD(i) float4 v##i = x4[blockBase + (i) * 256 + t];
    LD(0) LD(1) LD(2) LD(3) LD(4) LD(5) LD(6) LD(7)
#undef LD

#define P4(i) pair_pass(v##i.x, v##i.y, lo, c); pair_pass(v##i.z, v##i.w, lo, c);
    #pragma unroll 1
    for (int seg = NSEG - 1; seg >= 0; --seg) {     // descending: 1 cmp/test
        const float lo = (float)seg * 0.2f;         // last pass lo == 0.0f
        P4(0) P4(1) P4(2) P4(3) P4(4) P4(5) P4(6) P4(7)
    }
#undef P4

    // Decode: stored = -(BIAS+rr); out = -stored - BIAS = rr.
#define ST(i) o4[blockBase + (i) * 256 + t] = \
        make_float4(-v##i.x - BIAS, -v##i.y - BIAS, -v##i.z - BIAS, -v##i.w - BIAS);
    ST(0) ST(1) ST(2) ST(3) ST(4) ST(5) ST(6) ST(7)
#undef ST
}

extern "C" void kernel_launch(void* const* d_in, const int* in_sizes, int n_in,
                              void* d_out, int out_size, void* d_ws, size_t ws_size,
                              hipStream_t stream) {
    const float* x = (const float*)d_in[0];
    const float* c = (const float*)d_in[1];
    float* out = (float*)d_out;
    int n = in_sizes[0];                 // 16777216
    int grid = n / (256 * PTS);          // 2048 blocks -> exactly resident

    spline_depth2_kernel<<<grid, 256, 0, stream>>>(x, c, out);
}

// Round 10
// 173.685 us; speedup vs baseline: 6.2286x; 1.0004x over previous
//
#include <hip/hip_runtime.h>

#define NGRIDF 4194304.0f      // 2^22
#define NSEG 5                 // 3.36 MB windows -> resident in 4 MB per-XCD L2
#define PTS 32                 // points per thread
#define BIAS 64.0f             // done-marker: store -(BIAS+rr) < 0

// Unaligned-capable 16B vector load (align-4 dwordx4 is legal on gfx9+)
typedef float f32x4u __attribute__((ext_vector_type(4), aligned(4)));

// Weight+dot from an already-gathered quad. fp path identical to R4/R5
// (validated absmax 0.0625): s = x*2^22 exact; sp2 = s+2 carries the
// reference's rounding; all subtractions provably exact.
__device__ __forceinline__ float finish(float p, f32x4u cv) {
    float s   = p * NGRIDF;
    int   b   = (int)s;
    float sp2 = s + 2.0f;
    float g   = sp2 - (float)(b + 1);      // in [1,2)
    float fr  = g - 1.0f;                  // exact (Sterbenz)
    float om  = 1.0f - fr;
    float fr2 = fr * fr, fr3 = fr2 * fr;
    float om2 = om * om,  om3 = om2 * om;
    float w1 = fmaf(3.0f, fr3, fmaf(-6.0f, fr2, 4.0f));
    float w2 = fmaf(3.0f, om3, fmaf(-6.0f, om2, 4.0f));
    float rr = om3 * cv.x;
    rr = fmaf(w1,  cv.y, rr);
    rr = fmaf(w2,  cv.z, rr);
    rr = fmaf(fr3, cv.w, rr);
    return -BIAS - rr;                     // done-marker, always < 0
}

// Depth-2 pair-pass: issue both exec-masked gathers back-to-back (only
// active lanes present addresses -- R6 lesson; loads stay in flight across
// exec toggles), then consume both. cv0/cv1 are short-lived locals read
// under the same condition that wrote them (R7/R8 lesson).
__device__ __forceinline__ void pair_pass(float& p0, float& p1, float lo,
                                          const float* __restrict__ c) {
    bool a0 = p0 >= lo, a1 = p1 >= lo;
    f32x4u cv0, cv1;
    if (a0) cv0 = *reinterpret_cast<const f32x4u*>(c + (int)(p0 * NGRIDF));
    if (a1) cv1 = *reinterpret_cast<const f32x4u*>(c + (int)(p1 * NGRIDF));
    if (a0) p0 = finish(p0, cv0);
    if (a1) p1 = finish(p1, cv1);
}

// Single-cohort persistent sweep at full occupancy:
// 2048 blocks * 256 thr = 524288 threads = 8 blocks/CU * 4 waves = 32 waves/CU.
// The seg loop is PINNED seg-major (R9 lesson: without pins the compiler
// interchanges to point-major to shrink register pressure, destroying the
// L2-resident window): sched_barrier(0) blocks instruction motion across
// pass boundaries; __syncthreads() locksteps the block's waves per pass.
__global__ __launch_bounds__(256, 8) void spline_pinned2_kernel(
    const float* __restrict__ x, const float* __restrict__ c,
    float* __restrict__ out)
{
    const int t = threadIdx.x;
    const int blockBase = blockIdx.x * (8 * 256);   // in float4 units
    const float4* __restrict__ x4 = reinterpret_cast<const float4*>(x);
    float4* __restrict__ o4 = reinterpret_cast<float4*>(out);

#define LD(i) float4 v##i = x4[blockBase + (i) * 256 + t];
    LD(0) LD(1) LD(2) LD(3) LD(4) LD(5) LD(6) LD(7)
#undef LD

#define P4(i) pair_pass(v##i.x, v##i.y, lo, c); pair_pass(v##i.z, v##i.w, lo, c);
    #pragma unroll 1
    for (int seg = NSEG - 1; seg >= 0; --seg) {     // descending: 1 cmp/test
        const float lo = (float)seg * 0.2f;         // last pass lo == 0.0f
        P4(0) P4(1) P4(2) P4(3) P4(4) P4(5) P4(6) P4(7)
        __builtin_amdgcn_sched_barrier(0);          // no motion across passes
        __syncthreads();                            // wave lockstep per pass
    }
#undef P4

    // Decode: stored = -(BIAS+rr); out = -stored - BIAS = rr.
#define ST(i) o4[blockBase + (i) * 256 + t] = \
        make_float4(-v##i.x - BIAS, -v##i.y - BIAS, -v##i.z - BIAS, -v##i.w - BIAS);
    ST(0) ST(1) ST(2) ST(3) ST(4) ST(5) ST(6) ST(7)
#undef ST
}

extern "C" void kernel_launch(void* const* d_in, const int* in_sizes, int n_in,
                              void* d_out, int out_size, void* d_ws, size_t ws_size,
                              hipStream_t stream) {
    const float* x = (const float*)d_in[0];
    const float* c = (const float*)d_in[1];
    float* out = (float*)d_out;
    int n = in_sizes[0];                 // 16777216
    int grid = n / (256 * PTS);          // 2048 blocks -> exactly resident

    spline_pinned2_kernel<<<grid, 256, 0, stream>>>(x, c, out);
}

// Round 11
// 166.530 us; speedup vs baseline: 6.4962x; 1.0430x over previous
//
#include <hip/hip_runtime.h>

#define NGRIDF 4194304.0f      // 2^22
#define NSEG 5                 // 3.36 MB windows -> resident in 4 MB per-XCD L2
#define PTS 32                 // points per thread
#define BIAS 64.0f             // done-marker: store -(BIAS+rr) < 0

// Unaligned-capable 16B vector load (align-4 dwordx4 is legal on gfx9+)
typedef float f32x4u __attribute__((ext_vector_type(4), aligned(4)));

// Weight+dot from an already-gathered quad. fp path identical to R4/R5
// (validated absmax 0.0625 for 6 rounds): s = x*2^22 exact; sp2 = s+2
// carries the reference's rounding; all subtractions provably exact.
// For garbage (inactive-lane) inputs this computes junk that the caller
// discards via cndmask -- all ops are safe on any float input.
__device__ __forceinline__ float finish(float p, f32x4u cv) {
    float s   = p * NGRIDF;
    int   b   = (int)s;
    float sp2 = s + 2.0f;
    float g   = sp2 - (float)(b + 1);      // in [1,2)
    float fr  = g - 1.0f;                  // exact (Sterbenz)
    float om  = 1.0f - fr;
    float fr2 = fr * fr, fr3 = fr2 * fr;
    float om2 = om * om,  om3 = om2 * om;
    float w1 = fmaf(3.0f, fr3, fmaf(-6.0f, fr2, 4.0f));
    float w2 = fmaf(3.0f, om3, fmaf(-6.0f, om2, 4.0f));
    float rr = om3 * cv.x;
    rr = fmaf(w1,  cv.y, rr);
    rr = fmaf(w2,  cv.z, rr);
    rr = fmaf(fr3, cv.w, rr);
    return -BIAS - rr;                     // done-marker, always < 0
}

// Depth-2 in ONE exec region (the R6/R9 lesson: fissioned masked loads with
// conditionally-defined locals break codegen/locality; R4/R5's good FETCH
// came from load+consume in one clean region). Enter if EITHER point is
// active; inside, everything is unconditional. An inactive point borrows its
// partner's index (j = a ? own : partner) -- always valid and in the current
// window, so no out-of-window HBM pulls. Both dwordx4 issue back-to-back;
// finish0 (~18 VALU) hides load1's latency (counted vmcnt(1)/vmcnt(0)).
__device__ __forceinline__ void pair_pass(float& p0, float& p1, float lo,
                                          const float* __restrict__ c) {
    bool a0 = p0 >= lo, a1 = p1 >= lo;
    if (a0 | a1) {
        int i0 = (int)(p0 * NGRIDF);
        int i1 = (int)(p1 * NGRIDF);
        int j0 = a0 ? i0 : i1;             // in-window substitute
        int j1 = a1 ? i1 : i0;
        f32x4u cv0 = *reinterpret_cast<const f32x4u*>(c + j0);
        f32x4u cv1 = *reinterpret_cast<const f32x4u*>(c + j1);
        float f0 = finish(p0, cv0);
        float f1 = finish(p1, cv1);
        p0 = a0 ? f0 : p0;
        p1 = a1 ? f1 : p1;
    }
}

// Single-cohort persistent sweep at full occupancy:
// 2048 blocks * 256 thr = 524288 threads = 8 blocks/CU * 4 waves = 32 waves/CU.
// All waves sweep the 5 coefficient segments together (descending lo), so the
// chip's gathers stay inside a ~3.4 MB L2-resident window per pass.
__global__ __launch_bounds__(256, 8) void spline_pairwin_kernel(
    const float* __restrict__ x, const float* __restrict__ c,
    float* __restrict__ out)
{
    const int t = threadIdx.x;
    const int blockBase = blockIdx.x * (8 * 256);   // in float4 units
    const float4* __restrict__ x4 = reinterpret_cast<const float4*>(x);
    float4* __restrict__ o4 = reinterpret_cast<float4*>(out);

#define LD(i) float4 v##i = x4[blockBase + (i) * 256 + t];
    LD(0) LD(1) LD(2) LD(3) LD(4) LD(5) LD(6) LD(7)
#undef LD

#define P4(i) pair_pass(v##i.x, v##i.y, lo, c); pair_pass(v##i.z, v##i.w, lo, c);
    #pragma unroll 1
    for (int seg = NSEG - 1; seg >= 0; --seg) {     // descending: 1 cmp/test
        const float lo = (float)seg * 0.2f;         // last pass lo == 0.0f
        P4(0) P4(1) P4(2) P4(3) P4(4) P4(5) P4(6) P4(7)
        __builtin_amdgcn_sched_barrier(0);          // no motion across passes
    }
#undef P4

    // Decode: stored = -(BIAS+rr); out = -stored - BIAS = rr.
#define ST(i) o4[blockBase + (i) * 256 + t] = \
        make_float4(-v##i.x - BIAS, -v##i.y - BIAS, -v##i.z - BIAS, -v##i.w - BIAS);
    ST(0) ST(1) ST(2) ST(3) ST(4) ST(5) ST(6) ST(7)
#undef ST
}

extern "C" void kernel_launch(void* const* d_in, const int* in_sizes, int n_in,
                              void* d_out, int out_size, void* d_ws, size_t ws_size,
                              hipStream_t stream) {
    const float* x = (const float*)d_in[0];
    const float* c = (const float*)d_in[1];
    float* out = (float*)d_out;
    int n = in_sizes[0];                 // 16777216
    int grid = n / (256 * PTS);          // 2048 blocks -> exactly resident

    spline_pairwin_kernel<<<grid, 256, 0, stream>>>(x, c, out);
}

// Round 12
// 108.162 us; speedup vs baseline: 10.0018x; 1.5396x over previous
//
#include <hip/hip_runtime.h>

#define NGRIDF 4194304.0f      // 2^22
#define NSEG 8                 // 2.1 MB windows (seg width 2^19 floats)
#define PTS 32                 // points per thread
#define BIAS 64.0f             // done-marker: store -(BIAS+rr) < 0

// Unaligned-capable 16B vector load (align-4 dwordx4 is legal on gfx9+)
typedef float f32x4u __attribute__((ext_vector_type(4), aligned(4)));

// R5's validated per-point pass, VERBATIM (absmax 0.0625 across 7 rounds):
// one exec-masked gather immediately consumed in the same region — the only
// gather shape that keeps L2 hit rate high (R6/R9/R10/R11 lesson).
__device__ __forceinline__ void proc(float& p, float lo,
                                     const float* __restrict__ c) {
    if (p >= lo) {
        float s   = p * NGRIDF;
        int   b   = (int)s;
        float sp2 = s + 2.0f;
        float g   = sp2 - (float)(b + 1);      // in [1,2)
        float fr  = g - 1.0f;                  // exact (Sterbenz)
        float om  = 1.0f - fr;
        float fr2 = fr * fr, fr3 = fr2 * fr;
        float om2 = om * om,  om3 = om2 * om;
        float w1 = fmaf(3.0f, fr3, fmaf(-6.0f, fr2, 4.0f));
        float w2 = fmaf(3.0f, om3, fmaf(-6.0f, om2, 4.0f));
        f32x4u cv = *reinterpret_cast<const f32x4u*>(c + b);   // 1x dwordx4
        float rr = om3 * cv.x;
        rr = fmaf(w1,  cv.y, rr);
        rr = fmaf(w2,  cv.z, rr);
        rr = fmaf(fr3, cv.w, rr);
        p = -BIAS - rr;                        // done-marker, always < 0
    }
}

// Single-cohort persistent sweep (R5 structure) + per-pass cooperative
// window prefetch: each block streams one 8 KB slice of the CURRENT window
// (coalesced dwordx4, all-lane) before its point sweep. With round-robin
// block->XCD dispatch, blocks {j, j+8, ...} land on XCD j and their slice
// ids (blockIdx>>3)&255 cover all 256 slices -> every XCD's L2 is filled by
// eager streaming loads instead of dependent-gather first-touch misses.
// Prefetch covers only current-window lines: no added footprint or FETCH.
__global__ __launch_bounds__(256, 8) void spline_prefetch_kernel(
    const float* __restrict__ x, const float* __restrict__ c,
    float* __restrict__ out)
{
    const int t = threadIdx.x;
    const int blockBase = blockIdx.x * (8 * 256);   // in float4 units
    const int slice = (blockIdx.x >> 3) & 255;      // per-XCD slice id
    const float4* __restrict__ x4 = reinterpret_cast<const float4*>(x);
    float4* __restrict__ o4 = reinterpret_cast<float4*>(out);

#define LD(i) float4 v##i = x4[blockBase + (i) * 256 + t];
    LD(0) LD(1) LD(2) LD(3) LD(4) LD(5) LD(6) LD(7)
#undef LD

    float pf = 0.0f;   // keeps prefetch loads live (folded at pass end)

#define P4(i) proc(v##i.x, lo, c); proc(v##i.y, lo, c); \
              proc(v##i.z, lo, c); proc(v##i.w, lo, c);
    #pragma unroll 1
    for (int seg = NSEG - 1; seg >= 0; --seg) {     // descending: 1 cmp/test
        const float lo = (float)seg * 0.125f;       // exact; last pass 0.0f
        // Issue the window-slice prefetch FIRST (non-blocking: consumed only
        // at pass end, after the sweep has hidden the fill latency).
        const float4* pc = reinterpret_cast<const float4*>(
            c + (seg << 19) + (slice << 11) + (t << 3));
        float4 q0 = pc[0];
        float4 q1 = pc[1];
        // Point sweep (R5 verbatim)
        P4(0) P4(1) P4(2) P4(3) P4(4) P4(5) P4(6) P4(7)
        // Fold prefetch results (loads landed during the sweep)
        pf += (q0.x + q0.y) + (q0.z + q0.w) + (q1.x + q1.y) + (q1.z + q1.w);
        __builtin_amdgcn_sched_barrier(0);          // no cross-pass motion
    }
#undef P4

    // Unreachable use of pf (c ~ N(0,1): |pf| << 1e30) -- prevents DCE of
    // the prefetch loads without perturbing output.
    if (pf > 1e30f) out[0] = 0.0f;

    // Decode: stored = -(BIAS+rr); out = -stored - BIAS = rr.
#define ST(i) o4[blockBase + (i) * 256 + t] = \
        make_float4(-v##i.x - BIAS, -v##i.y - BIAS, -v##i.z - BIAS, -v##i.w - BIAS);
    ST(0) ST(1) ST(2) ST(3) ST(4) ST(5) ST(6) ST(7)
#undef ST
}

extern "C" void kernel_launch(void* const* d_in, const int* in_sizes, int n_in,
                              void* d_out, int out_size, void* d_ws, size_t ws_size,
                              hipStream_t stream) {
    const float* x = (const float*)d_in[0];
    const float* c = (const float*)d_in[1];
    float* out = (float*)d_out;
    int n = in_sizes[0];                 // 16777216
    int grid = n / (256 * PTS);          // 2048 blocks -> exactly resident

    spline_prefetch_kernel<<<grid, 256, 0, stream>>>(x, c, out);
}